// Round 4
// baseline (899.587 us; speedup 1.0000x reference)
//
#include <hip/hip_runtime.h>
#include <hip/hip_bf16.h>

typedef unsigned short u16;
typedef __attribute__((ext_vector_type(8))) short bf16x8;   // 8 bf16 = 4 VGPRs
typedef __attribute__((ext_vector_type(8))) unsigned short u16x8;
typedef __attribute__((ext_vector_type(4))) float f32x4;

#define NHh 12
#define KDd 64
#define Bb 64
#define Nn 1024
#define Cc 768
#define Oo 1548          // (1+2*64)*12
#define Mm 65536         // B*N

__device__ __forceinline__ float bf2f(u16 u) {
    union { unsigned int i; float f; } x; x.i = ((unsigned int)u) << 16; return x.f;
}
__device__ __forceinline__ u16 f2bf(float f) {
    union { float f; unsigned int i; } x; x.f = f;
    unsigned int r = x.i + 0x7fffu + ((x.i >> 16) & 1u);  // RNE
    return (u16)(r >> 16);
}
// packed f32x2 -> bf16x2 (RNE), src0 in low half
__device__ __forceinline__ unsigned int cvtpk(float a, float b) {
    unsigned int r;
    asm("v_cvt_pk_bf16_f32 %0, %1, %2" : "=v"(r) : "v"(a), "v"(b));
    return r;
}

__device__ __forceinline__ void async16(const u16* g, u16* l) {
    __builtin_amdgcn_global_load_lds(
        (const __attribute__((address_space(1))) void*)g,
        (__attribute__((address_space(3))) void*)l, 16, 0, 0);
}

// ---- dtype detect: even-index u16s of a bf16 buffer are bf16 values (narrow
// exponent band); of an fp32 buffer they are uniform mantissa bits (~25% band hit).
__global__ void detect_kernel(const u16* __restrict__ w, int* __restrict__ flag)
{
    __shared__ int cnt;
    if (threadIdx.x == 0) cnt = 0;
    __syncthreads();
    int c = 0;
#pragma unroll
    for (int i = 0; i < 4; ++i) {
        const u16 u = w[(threadIdx.x * 4 + i) * 2];
        const int e = (u >> 7) & 0xFF;
        c += ((e >= 0x60 && e <= 0x9F) || u == 0) ? 1 : 0;
    }
    atomicAdd(&cnt, c);
    __syncthreads();
    if (threadIdx.x == 0) flag[0] = (cnt >= 160) ? 1 : 0;   // 1 => bf16 buffers
}

// fp32 -> bf16 streaming convert, 16 elems/thread. Early-out if inputs are bf16.
__global__ __launch_bounds__(256) void cvt_kernel(
    const float* __restrict__ src, u16* __restrict__ dst, int n16,
    const int* __restrict__ flagp)
{
    if (flagp[0]) return;
    const int i = blockIdx.x * 256 + threadIdx.x;
    if (i >= n16) return;
    const float* p = src + (size_t)i * 16;
    const f32x4 a0 = *(const f32x4*)p;
    const f32x4 a1 = *(const f32x4*)(p + 4);
    const f32x4 a2 = *(const f32x4*)(p + 8);
    const f32x4 a3 = *(const f32x4*)(p + 12);
    union { unsigned int u[8]; u16x8 v[2]; } pk;
    pk.u[0] = cvtpk(a0[0], a0[1]); pk.u[1] = cvtpk(a0[2], a0[3]);
    pk.u[2] = cvtpk(a1[0], a1[1]); pk.u[3] = cvtpk(a1[2], a1[3]);
    pk.u[4] = cvtpk(a2[0], a2[1]); pk.u[5] = cvtpk(a2[2], a2[3]);
    pk.u[6] = cvtpk(a3[0], a3[1]); pk.u[7] = cvtpk(a3[2], a3[3]);
    *(u16x8*)(dst + (size_t)i * 16)     = pk.v[0];
    *(u16x8*)(dst + (size_t)i * 16 + 8) = pk.v[1];
}

// C[m,o] = sum_k A[m,k]*B[o,k] (+ bias[o]); row-major, contract last dims.
// 256x128 tile, BK=64, 8 waves (4M x 2N), double-buffered LDS (96 KiB).
// Minimum-2-phase pipeline (catalog T3 recipe): per K-tile, issue next tile's
// 6 global_load_lds FIRST, then ds_read+MFMA the current buffer, then one
// vmcnt(0)+s_barrier. Next tile's loads are in flight for the whole MFMA
// phase, so load latency hides under compute; one drain+barrier per tile.
// XOR chunk-swizzle on the global source column keeps ds_read_b128
// conflict-free (verified r1/r2: SQ_LDS_BANK_CONFLICT == 0).
// EPI=1: scatter into Qf (fp32), Kb (bf16), Vb (bf16, packed m x 768)
// EPI=2: store bf16 to Cout16 or fp32 to Cout32 per flag.
template <int EPI>
__global__ __launch_bounds__(512, 2) void gemm_bt(
    const void* __restrict__ Aorig, const u16* __restrict__ Acvt,
    const void* __restrict__ Borig, const u16* __restrict__ Bcvt,
    const void* __restrict__ biasv, const int* __restrict__ flagp,
    int Nout, int K, int lda, int ldb, int ntn,
    float* __restrict__ Qf, u16* __restrict__ Kb, u16* __restrict__ Vb,
    u16* __restrict__ Cout16, float* __restrict__ Cout32, int ldc)
{
    __shared__ __align__(16) u16 lA2[2 * 256 * 64];   // 65536 B
    __shared__ __align__(16) u16 lB2[2 * 128 * 64];   // 32768 B

    const int isbf = flagp[0];
    const u16* A  = isbf ? (const u16*)Aorig : Acvt;
    const u16* Bp = isbf ? (const u16*)Borig : Bcvt;

    const int t = threadIdx.x;
    const int lane = t & 63, wave = t >> 6;

    // XCD-chunked bijective swizzle (grid multiple of 8): consecutive tn
    // (same A panel) co-resident on one XCD.
    int bid = blockIdx.x;
    {
        const int nwg = (int)gridDim.x;
        const int cpx = nwg >> 3;
        bid = (bid & 7) * cpx + (bid >> 3);
    }
    const int tm = bid / ntn, tn = bid % ntn;
    const int m0 = tm * 256, o0 = tn * 128;

    const int srow = t >> 3;        // 0..63  (staging row within 64-row chunk)
    const int scol = (t & 7) * 8;   // staging col (elements), linear slot
    const int ssw  = (((t & 7) ^ (srow & 7)) * 8); // swizzled source col

    const int wr = wave >> 1, wc = wave & 1;       // 4M x 2N wave grid
    const int R0 = wr * 64, C0 = wc * 64;          // per-wave 64x64 output
    const int lr = lane & 15, lq = lane >> 4;
    const int sw8 = lr & 7;

    // staging sources (6 global_load_lds per thread per K-tile)
    const u16* aSrc[4];
    const u16* bSrc[2];
#pragma unroll
    for (int i = 0; i < 4; ++i)
        aSrc[i] = A + (size_t)(m0 + i * 64 + srow) * lda + ssw;
#pragma unroll
    for (int i = 0; i < 2; ++i) {
        int o = o0 + i * 64 + srow;
        if (o > Nout - 1) o = Nout - 1;
        bSrc[i] = Bp + (size_t)o * ldb + ssw;
    }

    f32x4 acc[4][4];
    const f32x4 zero = {0.f, 0.f, 0.f, 0.f};
#pragma unroll
    for (int i = 0; i < 4; ++i)
#pragma unroll
        for (int j = 0; j < 4; ++j) acc[i][j] = zero;

    auto STAGE = [&](int kt, int buf) {
        const int k0 = kt * 64;
        u16* la = &lA2[buf * (256 * 64)];
        u16* lb = &lB2[buf * (128 * 64)];
#pragma unroll
        for (int i = 0; i < 4; ++i)
            async16(aSrc[i] + k0, &la[(i * 64 + srow) * 64 + scol]);
#pragma unroll
        for (int i = 0; i < 2; ++i)
            async16(bSrc[i] + k0, &lb[(i * 64 + srow) * 64 + scol]);
    };

    const int NT = K >> 6;          // 12
    STAGE(0, 0);
    asm volatile("s_waitcnt vmcnt(0)" ::: "memory");
    __builtin_amdgcn_s_barrier();
    __builtin_amdgcn_sched_barrier(0);

    for (int kt = 0; kt < NT; ++kt) {
        const int cur = kt & 1;
        // issue next tile's loads first — they fly during this tile's MFMA.
        // Writing buf cur^1 is safe: the barrier at the end of iteration kt-1
        // guaranteed all waves finished reading it.
        if (kt + 1 < NT) STAGE(kt + 1, cur ^ 1);
        __builtin_amdgcn_sched_barrier(0);

        const u16* la = &lA2[cur * (256 * 64)];
        const u16* lb = &lB2[cur * (128 * 64)];
        __builtin_amdgcn_s_setprio(1);
#pragma unroll
        for (int kk = 0; kk < 2; ++kk) {
            bf16x8 af[4], bfr[4];
            const int sl = (((kk * 4 + lq) ^ sw8) * 8);
#pragma unroll
            for (int i = 0; i < 4; ++i)
                af[i] = *(const bf16x8*)&la[(R0 + i * 16 + lr) * 64 + sl];
#pragma unroll
            for (int j = 0; j < 4; ++j)
                bfr[j] = *(const bf16x8*)&lb[(C0 + j * 16 + lr) * 64 + sl];
#pragma unroll
            for (int i = 0; i < 4; ++i)
#pragma unroll
                for (int j = 0; j < 4; ++j)
                    acc[i][j] = __builtin_amdgcn_mfma_f32_16x16x32_bf16(af[i], bfr[j], acc[i][j], 0, 0, 0);
        }
        __builtin_amdgcn_s_setprio(0);
        __builtin_amdgcn_sched_barrier(0);
        // next tile's staging complete + all waves done reading buf cur
        asm volatile("s_waitcnt vmcnt(0)" ::: "memory");
        __builtin_amdgcn_s_barrier();
    }

    // epilogue: C/D layout col=lane&15, row=(lane>>4)*4+reg
#pragma unroll
    for (int i = 0; i < 4; ++i) {
#pragma unroll
        for (int j = 0; j < 4; ++j) {
            const int ob = o0 + C0 + j * 16 + lr;
            float bv = 0.f;
            if (ob < Nout)
                bv = isbf ? bf2f(((const u16*)biasv)[ob]) : ((const float*)biasv)[ob];
#pragma unroll
            for (int r = 0; r < 4; ++r) {
                const int row = m0 + R0 + i * 16 + lq * 4 + r;
                const float val = acc[i][j][r] + bv;
                if (EPI == 1) {
                    if (ob < Nout) {
                        const int h = ob / 129;
                        const int rr = ob - h * 129;
                        const size_t mh = (size_t)row * 12 + h;
                        if (rr == 0)       Qf[mh] = val;
                        else if (rr <= 64) Kb[mh * 64 + (rr - 1)]  = f2bf(val);
                        else               Vb[mh * 64 + (rr - 65)] = f2bf(val);
                    }
                } else {
                    if (isbf) Cout16[(size_t)row * ldc + ob] = f2bf(val);
                    else      Cout32[(size_t)row * ldc + ob] = val;
                }
            }
        }
    }
}

// one block per (b,h): softmax over n of q, then cv[d] = sum_n p_n * wcv_n * K[b,n,h,d] / sum
// K-reduce: thread owns a d-octet (u16x8 loads, 128B contiguous per 8 lanes),
// 32 n-rows per iteration; LDS transpose-reduce over the 32 n-groups.
__global__ __launch_bounds__(256) void softmax_cv_kernel(
    const float* __restrict__ Qf, const u16* __restrict__ Kb,
    const void* __restrict__ wcvv, const int* __restrict__ flagp,
    float* __restrict__ cv)
{
    const int isbf = flagp[0];
    const int bh = blockIdx.x;            // 0..767
    const int b = bh / NHh, h = bh - (bh / NHh) * NHh;
    const int t = threadIdx.x;

    __shared__ float sp[1024];
    __shared__ float red[256];
    __shared__ float redd[64 * 33];

    float q[4];
#pragma unroll
    for (int i = 0; i < 4; ++i) {
        const int n = t + i * 256;
        q[i] = Qf[(size_t)(b * Nn + n) * NHh + h];
    }
    float mx = fmaxf(fmaxf(q[0], q[1]), fmaxf(q[2], q[3]));
    red[t] = mx; __syncthreads();
    for (int off = 128; off; off >>= 1) {
        if (t < off) red[t] = fmaxf(red[t], red[t + off]);
        __syncthreads();
    }
    mx = red[0];
    __syncthreads();

    float sloc = 0.f;
#pragma unroll
    for (int i = 0; i < 4; ++i) {
        const int n = t + i * 256;
        const float e = __expf(q[i] - mx);
        sloc += e;
        const float wv = isbf ? bf2f(((const u16*)wcvv)[n]) : ((const float*)wcvv)[n];
        sp[n] = e * wv;
    }
    red[t] = sloc; __syncthreads();
    for (int off = 128; off; off >>= 1) {
        if (t < off) red[t] += red[t + off];
        __syncthreads();
    }
    const float s = red[0];
    __syncthreads();

    // vectorized K-reduce: d-octet per thread, 32 rows per pass
    const int dt8 = (t & 7) * 8;          // d base (0,8,..,56)
    const int ng  = t >> 3;               // n-group 0..31
    float a8[8];
#pragma unroll
    for (int i = 0; i < 8; ++i) a8[i] = 0.f;
    const u16* Kbase = Kb + ((size_t)b * Nn * NHh + h) * 64 + dt8;
#pragma unroll 4
    for (int it = 0; it < 32; ++it) {
        const int n = it * 32 + ng;
        const u16x8 kv = *(const u16x8*)(Kbase + (size_t)n * 768);
        const float p = sp[n];
#pragma unroll
        for (int i = 0; i < 8; ++i) a8[i] = fmaf(bf2f(kv[i]), p, a8[i]);
    }
#pragma unroll
    for (int i = 0; i < 8; ++i) redd[(dt8 + i) * 33 + ng] = a8[i];
    __syncthreads();
    if (t < 64) {
        float tot = 0.f;
#pragma unroll 8
        for (int g2 = 0; g2 < 32; ++g2) tot += redd[t * 33 + g2];
        cv[(size_t)bh * 64 + t] = tot / s;
    }
}

// in-place V[m, c] = relu(V[m,c]) * cv[(b*12+h)*64+d],  c = h*64+d, b = m>>10
__global__ __launch_bounds__(256) void relu_cv_kernel(
    u16* __restrict__ Vb, const float* __restrict__ cv)
{
    const size_t idx = ((size_t)blockIdx.x * 256 + threadIdx.x) * 8;
    const int c = (int)(idx % 768);
    const size_t m = idx / 768;
    const int b = (int)(m >> 10);
    const int h = c >> 6, d0 = c & 63;
    const float* cvp = cv + ((size_t)b * NHh + h) * 64 + d0;

    u16x8 r = *(const u16x8*)(Vb + idx);
#pragma unroll
    for (int i = 0; i < 8; ++i) {
        const float f = fmaxf(bf2f(r[i]), 0.f) * cvp[i];
        r[i] = f2bf(f);
    }
    *(u16x8*)(Vb + idx) = r;
}

extern "C" void kernel_launch(void* const* d_in, const int* in_sizes, int n_in,
                              void* d_out, int out_size, void* d_ws, size_t ws_size,
                              hipStream_t stream)
{
    const void* x     = d_in[0];
    const void* w_qkv = d_in[1];
    const void* b_qkv = d_in[2];
    const void* w_cv  = d_in[3];
    const void* w_out = d_in[4];
    const void* b_out = d_in[5];

    char* w = (char*)d_ws;
    float* Qf = (float*)w;                                   // 65536*12*4   = 3,145,728 B
    u16*   Kb = (u16*)(w + 3145728);                          // 65536*768*2  = 100,663,296 B
    u16*   Vb = (u16*)(w + 3145728 + 100663296);              // 100,663,296 B
    float* cv = (float*)(w + 3145728 + 2ll * 100663296);      // 768*64*4     = 196,608 B
    int* flag = (int*)(w + 3145728 + 2ll * 100663296 + 196608);
    u16* wqkvb = (u16*)(w + 3145728 + 2ll * 100663296 + 196608 + 4096);  // 1548*768*2 = 2,377,728 B
    u16* woutb = (u16*)((char*)wqkvb + 2377728);                         // 768*768*2  = 1,179,648 B

    // x-bf16 buffer aliases d_out: 100,663,296 B needed, d_out is 201 MB fp32,
    // dead until GEMM2's store (which runs strictly after GEMM1 reads xb).
    u16* xb = (u16*)d_out;

    // dtype detect (bf16 vs fp32 buffers)
    detect_kernel<<<1, 64, 0, stream>>>((const u16*)w_qkv, flag);

    // fp32 -> bf16 pre-convert (no-ops if inputs already bf16)
    cvt_kernel<<<(Mm * Cc) / (256 * 16), 256, 0, stream>>>((const float*)x, xb, (Mm * Cc) / 16, flag);
    cvt_kernel<<<(Oo * Cc + 256 * 16 - 1) / (256 * 16), 256, 0, stream>>>((const float*)w_qkv, wqkvb, (Oo * Cc) / 16, flag);
    cvt_kernel<<<(Cc * Cc) / (256 * 16), 256, 0, stream>>>((const float*)w_out, woutb, (Cc * Cc) / 16, flag);

    // GEMM1: qkv = x @ w_qkv^T + b_qkv, scattered into Qf/Kb/Vb
    gemm_bt<1><<<256 * 13, 512, 0, stream>>>(x, xb, w_qkv, wqkvb, b_qkv, flag,
        Oo, Cc, Cc, Cc, 13, Qf, Kb, Vb, nullptr, nullptr, 0);

    // softmax over n + cv reduction
    softmax_cv_kernel<<<Bb * NHh, 256, 0, stream>>>(Qf, Kb, w_cv, flag, cv);

    // t = relu(v) * cv, in place on Vb
    relu_cv_kernel<<<(Mm * 768) / (256 * 8), 256, 0, stream>>>(Vb, cv);

    // GEMM2: out = t @ w_out^T + b_out  (A = Vb, always internal bf16)
    gemm_bt<2><<<256 * 6, 512, 0, stream>>>(Vb, (const u16*)Vb, w_out, woutb, b_out, flag,
        Cc, Cc, Cc, Cc, 6, nullptr, nullptr, nullptr, (u16*)d_out, (float*)d_out, Cc);
}

// Round 5
// 804.605 us; speedup vs baseline: 1.1180x; 1.1180x over previous
//
#include <hip/hip_runtime.h>
#include <hip/hip_bf16.h>

typedef unsigned short u16;
typedef __attribute__((ext_vector_type(8))) short bf16x8;   // 8 bf16 = 4 VGPRs
typedef __attribute__((ext_vector_type(8))) unsigned short u16x8;
typedef __attribute__((ext_vector_type(4))) float f32x4;

#define NHh 12
#define KDd 64
#define Bb 64
#define Nn 1024
#define Cc 768
#define Oo 1548          // (1+2*64)*12
#define Mm 65536         // B*N

__device__ __forceinline__ float bf2f(u16 u) {
    union { unsigned int i; float f; } x; x.i = ((unsigned int)u) << 16; return x.f;
}
__device__ __forceinline__ u16 f2bf(float f) {
    union { float f; unsigned int i; } x; x.f = f;
    unsigned int r = x.i + 0x7fffu + ((x.i >> 16) & 1u);  // RNE
    return (u16)(r >> 16);
}
// packed f32x2 -> bf16x2 (RNE), src0 in low half
__device__ __forceinline__ unsigned int cvtpk(float a, float b) {
    unsigned int r;
    asm("v_cvt_pk_bf16_f32 %0, %1, %2" : "=v"(r) : "v"(a), "v"(b));
    return r;
}

__device__ __forceinline__ void async16(const u16* g, u16* l) {
    __builtin_amdgcn_global_load_lds(
        (const __attribute__((address_space(1))) void*)g,
        (__attribute__((address_space(3))) void*)l, 16, 0, 0);
}

// ---- dtype detect: even-index u16s of a bf16 buffer are bf16 values (narrow
// exponent band); of an fp32 buffer they are uniform mantissa bits (~25% band hit).
__global__ void detect_kernel(const u16* __restrict__ w, int* __restrict__ flag)
{
    __shared__ int cnt;
    if (threadIdx.x == 0) cnt = 0;
    __syncthreads();
    int c = 0;
#pragma unroll
    for (int i = 0; i < 4; ++i) {
        const u16 u = w[(threadIdx.x * 4 + i) * 2];
        const int e = (u >> 7) & 0xFF;
        c += ((e >= 0x60 && e <= 0x9F) || u == 0) ? 1 : 0;
    }
    atomicAdd(&cnt, c);
    __syncthreads();
    if (threadIdx.x == 0) flag[0] = (cnt >= 160) ? 1 : 0;   // 1 => bf16 buffers
}

#define NX16 3145728   // x      elems/16
#define NQ16 74304     // w_qkv  elems/16
#define NO16 36864     // w_out  elems/16

__device__ __forceinline__ void cvt16(const float* p, u16* d)
{
    const f32x4 a0 = *(const f32x4*)p;
    const f32x4 a1 = *(const f32x4*)(p + 4);
    const f32x4 a2 = *(const f32x4*)(p + 8);
    const f32x4 a3 = *(const f32x4*)(p + 12);
    union { unsigned int u[8]; u16x8 v[2]; } pk;
    pk.u[0] = cvtpk(a0[0], a0[1]); pk.u[1] = cvtpk(a0[2], a0[3]);
    pk.u[2] = cvtpk(a1[0], a1[1]); pk.u[3] = cvtpk(a1[2], a1[3]);
    pk.u[4] = cvtpk(a2[0], a2[1]); pk.u[5] = cvtpk(a2[2], a2[3]);
    pk.u[6] = cvtpk(a3[0], a3[1]); pk.u[7] = cvtpk(a3[2], a3[3]);
    *(u16x8*)d       = pk.v[0];
    *(u16x8*)(d + 8) = pk.v[1];
}

// single fused fp32->bf16 convert for x, w_qkv, w_out. No-op if inputs bf16.
__global__ __launch_bounds__(256) void cvt3_kernel(
    const float* __restrict__ x,  u16* __restrict__ xb,
    const float* __restrict__ wq, u16* __restrict__ wqb,
    const float* __restrict__ wo, u16* __restrict__ wob,
    const int* __restrict__ flagp)
{
    if (flagp[0]) return;
    const int i = blockIdx.x * 256 + threadIdx.x;
    if (i < NX16) {
        cvt16(x + (size_t)i * 16, xb + (size_t)i * 16);
    } else if (i < NX16 + NQ16) {
        const int j = i - NX16;
        cvt16(wq + (size_t)j * 16, wqb + (size_t)j * 16);
    } else if (i < NX16 + NQ16 + NO16) {
        const int j = i - NX16 - NQ16;
        cvt16(wo + (size_t)j * 16, wob + (size_t)j * 16);
    }
}

// C[m,o] = sum_k A[m,k]*B[o,k] (+ bias[o]); row-major, contract last dims.
// 128x128 tile, BK=32, 4 waves (2x2), double-buffered LDS (32 KiB total ->
// same ~3 blocks/CU occupancy as the measured-611TF r2 kernel, but staging
// of tile kt+1 is issued BEFORE tile kt's MFMA phase and overlaps it; one
// vmcnt(0)+barrier per K-iter (r2 had two barriers and serial staging).
// LDS swizzle for BK=32 (4 chunks of 16B per row): chunk' = chunk ^
// ((row ^ row>>2) & 3). Gives the uniform 8-lanes-per-bank-quad floor on
// ds_read_b128 (same distribution as the r1/r2 BK=64 scheme that measured
// SQ_LDS_BANK_CONFLICT == 0). global_load_lds keeps a LINEAR dest
// (lane*16B); the swizzle is applied to the global source column and the
// ds_read address (rule #21: same involution on both sides).
// EPI=1: scatter into Qf (fp32), Kb (bf16), Vb (bf16, packed m x 768)
// EPI=2: store bf16 to Cout16 or fp32 to Cout32 per flag.
template <int EPI>
__global__ __launch_bounds__(256, 4) void gemm_bt(
    const void* __restrict__ Aorig, const u16* __restrict__ Acvt,
    const void* __restrict__ Borig, const u16* __restrict__ Bcvt,
    const void* __restrict__ biasv, const int* __restrict__ flagp,
    int Nout, int K, int lda, int ldb, int ntn,
    float* __restrict__ Qf, u16* __restrict__ Kb, u16* __restrict__ Vb,
    u16* __restrict__ Cout16, float* __restrict__ Cout32, int ldc)
{
    __shared__ __align__(16) u16 lA2[2 * 128 * 32];   // 16 KiB
    __shared__ __align__(16) u16 lB2[2 * 128 * 32];   // 16 KiB

    const int isbf = flagp[0];
    const u16* A  = isbf ? (const u16*)Aorig : Acvt;
    const u16* Bp = isbf ? (const u16*)Borig : Bcvt;

    const int t = threadIdx.x;
    const int lane = t & 63, wave = t >> 6;

    // XCD-chunked bijective swizzle (grid multiple of 8): consecutive tn
    // (same A panel) co-resident on one XCD.
    int bid = blockIdx.x;
    {
        const int nwg = (int)gridDim.x;
        const int cpx = nwg >> 3;
        bid = (bid & 7) * cpx + (bid >> 3);
    }
    const int tm = bid / ntn, tn = bid % ntn;
    const int m0 = tm * 128, o0 = tn * 128;

    // staging: thread t stages 16B chunk (t&3) of local rows (t>>2), (t>>2)+64
    const int srow = t >> 2;                                  // 0..63
    const int scc  = t & 3;
    const int ssw  = (scc ^ ((srow ^ (srow >> 2)) & 3)) * 8;  // swizzled src col
    const int sdst = t * 8;                                   // linear LDS dest

    const int R0 = (wave >> 1) * 64, C0 = (wave & 1) * 64;
    const int lr = lane & 15, lq = lane >> 4;
    const int sw2 = (lr ^ (lr >> 2)) & 3;                     // s(row) for all fragment rows
    const int sl  = (lq ^ sw2) * 8;                           // swizzled read slot (elems)

    // staging sources (4 global_load_lds per thread per K-tile)
    const u16* aS0 = A + (size_t)(m0 + srow) * lda + ssw;
    const u16* aS1 = A + (size_t)(m0 + 64 + srow) * lda + ssw;
    int ob0 = o0 + srow;      if (ob0 > Nout - 1) ob0 = Nout - 1;
    int ob1 = o0 + 64 + srow; if (ob1 > Nout - 1) ob1 = Nout - 1;
    const u16* bS0 = Bp + (size_t)ob0 * ldb + ssw;
    const u16* bS1 = Bp + (size_t)ob1 * ldb + ssw;

    f32x4 acc[4][4];
    const f32x4 zero = {0.f, 0.f, 0.f, 0.f};
#pragma unroll
    for (int i = 0; i < 4; ++i)
#pragma unroll
        for (int j = 0; j < 4; ++j) acc[i][j] = zero;

    auto STAGE = [&](int kt, int buf) {
        const int k0 = kt * 32;
        u16* la = &lA2[buf * (128 * 32)];
        u16* lb = &lB2[buf * (128 * 32)];
        async16(aS0 + k0, &la[sdst]);
        async16(aS1 + k0, &la[sdst + 64 * 32]);
        async16(bS0 + k0, &lb[sdst]);
        async16(bS1 + k0, &lb[sdst + 64 * 32]);
    };

    const int NT = K >> 5;          // 24
    STAGE(0, 0);
    asm volatile("s_waitcnt vmcnt(0)" ::: "memory");
    __builtin_amdgcn_s_barrier();
    __builtin_amdgcn_sched_barrier(0);

    for (int kt = 0; kt < NT; ++kt) {
        const int cur = kt & 1;
        // issue next tile's loads first — they fly during this tile's MFMA.
        // Writing buf cur^1 is safe: the barrier ending iter kt-1 guaranteed
        // every wave finished its ds_reads of that buffer.
        if (kt + 1 < NT) STAGE(kt + 1, cur ^ 1);
        __builtin_amdgcn_sched_barrier(0);

        const u16* la = &lA2[cur * (128 * 32)];
        const u16* lb = &lB2[cur * (128 * 32)];
        __builtin_amdgcn_s_setprio(1);
        {
            bf16x8 af[4], bfr[4];
#pragma unroll
            for (int i = 0; i < 4; ++i)
                af[i] = *(const bf16x8*)&la[(R0 + i * 16 + lr) * 32 + sl];
#pragma unroll
            for (int j = 0; j < 4; ++j)
                bfr[j] = *(const bf16x8*)&lb[(C0 + j * 16 + lr) * 32 + sl];
#pragma unroll
            for (int i = 0; i < 4; ++i)
#pragma unroll
                for (int j = 0; j < 4; ++j)
                    acc[i][j] = __builtin_amdgcn_mfma_f32_16x16x32_bf16(af[i], bfr[j], acc[i][j], 0, 0, 0);
        }
        __builtin_amdgcn_s_setprio(0);
        __builtin_amdgcn_sched_barrier(0);
        // next tile's staging landed + all waves done reading buf cur
        asm volatile("s_waitcnt vmcnt(0)" ::: "memory");
        __builtin_amdgcn_s_barrier();
    }

    // epilogue: C/D layout col=lane&15, row=(lane>>4)*4+reg. j-outer so the
    // ob/h/rr/bias work is computed once per j instead of once per (i,j).
#pragma unroll
    for (int j = 0; j < 4; ++j) {
        const int ob = o0 + C0 + j * 16 + lr;
        const bool valid = (ob < Nout);
        float bv = 0.f;
        int h = 0, rr = 0;
        if (valid) {
            bv = isbf ? bf2f(((const u16*)biasv)[ob]) : ((const float*)biasv)[ob];
            if (EPI == 1) { h = ob / 129; rr = ob - h * 129; }
        }
#pragma unroll
        for (int i = 0; i < 4; ++i) {
#pragma unroll
            for (int r = 0; r < 4; ++r) {
                const int row = m0 + R0 + i * 16 + lq * 4 + r;
                const float val = acc[i][j][r] + bv;
                if (EPI == 1) {
                    if (valid) {
                        const size_t mh = (size_t)row * 12 + h;
                        if (rr == 0)       Qf[mh] = val;
                        else if (rr <= 64) Kb[mh * 64 + (rr - 1)]  = f2bf(val);
                        else               Vb[mh * 64 + (rr - 65)] = f2bf(val);
                    }
                } else {
                    if (isbf) Cout16[(size_t)row * ldc + ob] = f2bf(val);
                    else      Cout32[(size_t)row * ldc + ob] = val;
                }
            }
        }
    }
}

// one block per (b,h): softmax over n of q, cv[d] = sum_n p_n*wcv_n*K[b,n,h,d]/sum,
// then (fused) V[b,n,h,d] = relu(V) * cv[d] in place — replaces the separate
// relu_cv kernel (saves 200 MB of extra traffic's kernel launch + pass).
// K/V access: thread owns a d-octet (u16x8, 128B contiguous per 8 lanes).
__global__ __launch_bounds__(256) void softmax_cv_kernel(
    const float* __restrict__ Qf, const u16* __restrict__ Kb,
    u16* __restrict__ Vb,
    const void* __restrict__ wcvv, const int* __restrict__ flagp)
{
    const int isbf = flagp[0];
    const int bh = blockIdx.x;            // 0..767
    const int b = bh / NHh, h = bh - (bh / NHh) * NHh;
    const int t = threadIdx.x;

    __shared__ float sp[1024];
    __shared__ float red[256];
    __shared__ float redd[64 * 33];
    __shared__ float cvs[64];

    float q[4];
#pragma unroll
    for (int i = 0; i < 4; ++i) {
        const int n = t + i * 256;
        q[i] = Qf[(size_t)(b * Nn + n) * NHh + h];
    }
    float mx = fmaxf(fmaxf(q[0], q[1]), fmaxf(q[2], q[3]));
    red[t] = mx; __syncthreads();
    for (int off = 128; off; off >>= 1) {
        if (t < off) red[t] = fmaxf(red[t], red[t + off]);
        __syncthreads();
    }
    mx = red[0];
    __syncthreads();

    float sloc = 0.f;
#pragma unroll
    for (int i = 0; i < 4; ++i) {
        const int n = t + i * 256;
        const float e = __expf(q[i] - mx);
        sloc += e;
        const float wv = isbf ? bf2f(((const u16*)wcvv)[n]) : ((const float*)wcvv)[n];
        sp[n] = e * wv;
    }
    red[t] = sloc; __syncthreads();
    for (int off = 128; off; off >>= 1) {
        if (t < off) red[t] += red[t + off];
        __syncthreads();
    }
    const float s = red[0];
    __syncthreads();

    // vectorized K-reduce: d-octet per thread, 32 rows per pass
    const int dt8 = (t & 7) * 8;          // d base (0,8,..,56)
    const int ng  = t >> 3;               // n-group 0..31
    float a8[8];
#pragma unroll
    for (int i = 0; i < 8; ++i) a8[i] = 0.f;
    const u16* Kbase = Kb + ((size_t)b * Nn * NHh + h) * 64 + dt8;
#pragma unroll 4
    for (int it = 0; it < 32; ++it) {
        const int n = it * 32 + ng;
        const u16x8 kv = *(const u16x8*)(Kbase + (size_t)n * 768);
        const float p = sp[n];
#pragma unroll
        for (int i = 0; i < 8; ++i) a8[i] = fmaf(bf2f(kv[i]), p, a8[i]);
    }
#pragma unroll
    for (int i = 0; i < 8; ++i) redd[(dt8 + i) * 33 + ng] = a8[i];
    __syncthreads();
    if (t < 64) {
        float tot = 0.f;
#pragma unroll 8
        for (int g2 = 0; g2 < 32; ++g2) tot += redd[t * 33 + g2];
        cvs[t] = tot / s;
    }
    __syncthreads();

    // fused: V[b, n, h, dt8..dt8+7] = relu(V) * cv, same octet ownership
    float c8[8];
#pragma unroll
    for (int i = 0; i < 8; ++i) c8[i] = cvs[dt8 + i];
    u16* Vp = Vb + ((size_t)b * Nn * NHh + h) * 64 + dt8;
#pragma unroll 4
    for (int it = 0; it < 32; ++it) {
        const int n = it * 32 + ng;
        u16x8 r = *(u16x8*)(Vp + (size_t)n * 768);
#pragma unroll
        for (int i = 0; i < 8; ++i) {
            const float f = fmaxf(bf2f(r[i]), 0.f) * c8[i];
            r[i] = f2bf(f);
        }
        *(u16x8*)(Vp + (size_t)n * 768) = r;
    }
}

extern "C" void kernel_launch(void* const* d_in, const int* in_sizes, int n_in,
                              void* d_out, int out_size, void* d_ws, size_t ws_size,
                              hipStream_t stream)
{
    const void* x     = d_in[0];
    const void* w_qkv = d_in[1];
    const void* b_qkv = d_in[2];
    const void* w_cv  = d_in[3];
    const void* w_out = d_in[4];
    const void* b_out = d_in[5];

    char* w = (char*)d_ws;
    float* Qf = (float*)w;                                   // 65536*12*4   = 3,145,728 B
    u16*   Kb = (u16*)(w + 3145728);                          // 65536*768*2  = 100,663,296 B
    u16*   Vb = (u16*)(w + 3145728 + 100663296);              // 100,663,296 B
    int* flag = (int*)(w + 3145728 + 2ll * 100663296 + 196608);
    u16* wqkvb = (u16*)(w + 3145728 + 2ll * 100663296 + 196608 + 4096);  // 1548*768*2 = 2,377,728 B
    u16* woutb = (u16*)((char*)wqkvb + 2377728);                         // 768*768*2  = 1,179,648 B

    // x-bf16 buffer aliases d_out: 100,663,296 B needed, d_out is 201 MB fp32,
    // dead until GEMM2's store (which runs strictly after GEMM1 reads xb).
    u16* xb = (u16*)d_out;

    // dtype detect (bf16 vs fp32 buffers)
    detect_kernel<<<1, 64, 0, stream>>>((const u16*)w_qkv, flag);

    // fused fp32 -> bf16 pre-convert (no-op if inputs already bf16)
    cvt3_kernel<<<(NX16 + NQ16 + NO16 + 255) / 256, 256, 0, stream>>>(
        (const float*)x, xb, (const float*)w_qkv, wqkvb, (const float*)w_out, woutb, flag);

    // GEMM1: qkv = x @ w_qkv^T + b_qkv, scattered into Qf/Kb/Vb
    gemm_bt<1><<<512 * 13, 256, 0, stream>>>(x, xb, w_qkv, wqkvb, b_qkv, flag,
        Oo, Cc, Cc, Cc, 13, Qf, Kb, Vb, nullptr, nullptr, 0);

    // softmax over n + cv reduction + fused relu(V)*cv in place
    softmax_cv_kernel<<<Bb * NHh, 256, 0, stream>>>(Qf, Kb, Vb, w_cv, flag);

    // GEMM2: out = t @ w_out^T + b_out  (A = Vb, always internal bf16)
    gemm_bt<2><<<512 * 6, 256, 0, stream>>>(Vb, (const u16*)Vb, w_out, woutb, b_out, flag,
        Cc, Cc, Cc, Cc, 6, nullptr, nullptr, nullptr, (u16*)d_out, (float*)d_out, Cc);
}